// Round 5
// baseline (200.269 us; speedup 1.0000x reference)
//
#include <hip/hip_runtime.h>
#include <hip/hip_bf16.h>

#define BB 16
#define NN 4096
#define DD 64
#define NM1 4095

typedef __bf16 bf16x8 __attribute__((ext_vector_type(8)));
typedef float f32x4 __attribute__((ext_vector_type(4)));

typedef __attribute__((address_space(1))) const void gas_void;
typedef __attribute__((address_space(3))) void las_void;

// ws layout:
//   [0]        float mx[4096]          (16 KB)  -- zeroed via memsetAsync
//   [16384]    float ss[4096]          (16 KB)  -- zeroed via memsetAsync
//   [32768]    __bf16 XT[16][64][4096] ( 8 MiB)
//   [+8 MiB]   __bf16 A16[4096][4096]  (32 MiB)

// ---------------------------------------------------------------------------
// Kernel 1: flat scatter build (f32 + bf16 copies), l1/l2 via atomics.
// ---------------------------------------------------------------------------
__global__ __launch_bounds__(256) void build_kernel(
    const float* __restrict__ inc, float* __restrict__ out_inc,
    __bf16* __restrict__ A16, float* __restrict__ mxa, float* __restrict__ ssa)
{
    int t = threadIdx.x;
    int base = blockIdx.x << 12;                 // 4096 elems per block
    int rA = (int)((unsigned)base / NM1);        // block spans rows {rA, rA+1}
    float pm0 = 0.f, ps0 = 0.f, pm1 = 0.f, ps1 = 0.f;
    #pragma unroll
    for (int j = 0; j < 16; ++j) {
        int f = base + j * 256 + t;
        int i = (int)((unsigned)f / NM1);
        int c = f - i * NM1;
        float x = inc[f];
        float w = x > 0.01f ? x : 0.f;
        int dst = f + i + (c >= i);              // i*4096 + c + (c>=i)
        out_inc[dst] = w;
        A16[dst] = (__bf16)w;
        if (i == rA) { pm0 = fmaxf(pm0, w); ps0 += w * w; }
        else         { pm1 = fmaxf(pm1, w); ps1 += w * w; }
    }
    #pragma unroll
    for (int off = 32; off; off >>= 1) {
        pm0 = fmaxf(pm0, __shfl_down(pm0, off));
        ps0 += __shfl_down(ps0, off);
        pm1 = fmaxf(pm1, __shfl_down(pm1, off));
        ps1 += __shfl_down(ps1, off);
    }
    __shared__ float sm0[4], sq0[4], sm1[4], sq1[4];
    int wid = t >> 6;
    if ((t & 63) == 0) { sm0[wid] = pm0; sq0[wid] = ps0; sm1[wid] = pm1; sq1[wid] = ps1; }
    __syncthreads();
    if (t == 0) {
        float m0v = fmaxf(fmaxf(sm0[0], sm0[1]), fmaxf(sm0[2], sm0[3]));
        float s0v = sq0[0] + sq0[1] + sq0[2] + sq0[3];
        float m1v = fmaxf(fmaxf(sm1[0], sm1[1]), fmaxf(sm1[2], sm1[3]));
        float s1v = sq1[0] + sq1[1] + sq1[2] + sq1[3];
        atomicMax((unsigned*)(mxa + rA), __float_as_uint(m0v));
        atomicAdd(ssa + rA, s0v);
        int rB = rA + 1;
        if (rB < NN) {
            atomicMax((unsigned*)(mxa + rB), __float_as_uint(m1v));
            atomicAdd(ssa + rB, s1v);
        }
    }
}

// ---------------------------------------------------------------------------
// Kernel 2: XT[b][d][n] = (bf16)X[b][n][d] + diagonal writes
// ---------------------------------------------------------------------------
__global__ __launch_bounds__(256) void xt_kernel(
    const float* __restrict__ X, __bf16* __restrict__ XT,
    float* __restrict__ out_inc, __bf16* __restrict__ A16)
{
    __shared__ __bf16 tile[64 * 72];
    int t = threadIdx.x;
    int ntile = blockIdx.x, b = blockIdx.y;
    int n = t >> 2, q = t & 3;
    const float* src = X + ((size_t)b * NN + ntile * 64 + n) * DD + q * 16;
    #pragma unroll
    for (int v = 0; v < 4; ++v) {
        f32x4 u = *(const f32x4*)(src + v * 4);
        #pragma unroll
        for (int j = 0; j < 4; ++j) {
            int d = q * 16 + v * 4 + j;
            tile[d * 72 + n] = (__bf16)u[j];
        }
    }
    __syncthreads();
    int d = t >> 2;
    __bf16* dst = XT + ((size_t)b * DD + d) * NN + ntile * 64 + q * 16;
    *(bf16x8*)dst       = *(bf16x8*)&tile[d * 72 + q * 16];
    *(bf16x8*)(dst + 8) = *(bf16x8*)&tile[d * 72 + q * 16 + 8];
    if (b == 0 && t < 64) {
        int r = ntile * 64 + t;
        out_inc[(size_t)r * NN + r] = 1.0f;
        A16[(size_t)r * NN + r] = (__bf16)1.0f;
    }
}

// ---------------------------------------------------------------------------
// Kernel 3: acc = A16 @ X[b] (MFMA, global_load_lds, XOR-swizzled octets),
//   fused xp = Xrows @ (r+I), loss epilogue.
//   Block tile 128 m x 64 n, BK=64, grid (32, 16) = 512 blocks (2/CU).
//   Wave tile 64 x 32: 4 m-frags x 2 n-frags (16x16x32) -> 21.8 FLOP/LDS-byte.
// ---------------------------------------------------------------------------
__global__ __launch_bounds__(256) void gemm_loss_kernel(
    const __bf16* __restrict__ A16, const __bf16* __restrict__ XT,
    const float* __restrict__ X, const float* __restrict__ rproj,
    const float* __restrict__ mxa, const float* __restrict__ ssa,
    float* __restrict__ loss)
{
    __shared__ __bf16 As[128 * 64];              // 16 KB, rows 128 B, swizzled
    __shared__ __bf16 Xs[64 * 64];               // 8 KB
    __shared__ float sred[128][2];

    int t = threadIdx.x;
    int wave = t >> 6, lane = t & 63;
    int quad = lane >> 4, ln = lane & 15;
    int m0 = blockIdx.x * 128;
    int b  = blockIdx.y;
    int mrow0 = (wave & 1) * 64;                 // wave m-offset
    int ncol0 = (wave >> 1) * 32;                // wave n-offset
    int sr = lane >> 3;                          // staging row-in-group
    int so = lane & 7;                           // staging octet

    const __bf16* Abase = A16 + (size_t)m0 * NN;
    const __bf16* Xbase = XT + (size_t)b * DD * NN;

    f32x4 acc[4][2];
    f32x4 zero = {0.f, 0.f, 0.f, 0.f};
    #pragma unroll
    for (int mt = 0; mt < 4; ++mt)
        #pragma unroll
        for (int nt = 0; nt < 2; ++nt) acc[mt][nt] = zero;

    for (int kt = 0; kt < NN / 64; ++kt) {
        int k0 = kt * 64;
        // A: 128 rows; each wave loads 32 (4 groups of 8)
        #pragma unroll
        for (int p = 0; p < 4; ++p) {
            int r0 = wave * 32 + p * 8;          // wave-uniform
            int r  = r0 + sr;
            int og = so ^ (r & 7);
            __builtin_amdgcn_global_load_lds(
                (gas_void*)(Abase + (size_t)r * NN + k0 + og * 8),
                (las_void*)(As + r0 * 64), 16, 0, 0);
        }
        // X: 64 rows; each wave loads 16
        #pragma unroll
        for (int p = 0; p < 2; ++p) {
            int r0 = wave * 16 + p * 8;
            int r  = r0 + sr;
            int og = so ^ (r & 7);
            __builtin_amdgcn_global_load_lds(
                (gas_void*)(Xbase + (size_t)r * NN + k0 + og * 8),
                (las_void*)(Xs + r0 * 64), 16, 0, 0);
        }
        __syncthreads();
        #pragma unroll
        for (int kk = 0; kk < 64; kk += 32) {
            int oc = (kk >> 3) + quad;
            bf16x8 af[4], bfr[2];
            #pragma unroll
            for (int mt = 0; mt < 4; ++mt) {
                int r = mrow0 + mt * 16 + ln;
                af[mt] = *(const bf16x8*)&As[r * 64 + ((oc ^ (r & 7)) << 3)];
            }
            #pragma unroll
            for (int nt = 0; nt < 2; ++nt) {
                int n = ncol0 + nt * 16 + ln;
                bfr[nt] = *(const bf16x8*)&Xs[n * 64 + ((oc ^ (n & 7)) << 3)];
            }
            #pragma unroll
            for (int mt = 0; mt < 4; ++mt)
                #pragma unroll
                for (int nt = 0; nt < 2; ++nt)
                    acc[mt][nt] = __builtin_amdgcn_mfma_f32_16x16x32_bf16(
                        af[mt], bfr[nt], acc[mt][nt], 0, 0, 0);
        }
        __syncthreads();
    }

    // ---- phase 2: xp = X[b][m0..m0+127][:] @ (r+I), same layout ----
    #pragma unroll
    for (int it = 0; it < 4; ++it) {
        int lin = it * 256 + t;                  // 0..1023
        int rr = lin >> 3;                       // 0..127
        int o  = lin & 7;
        const float* src = X + ((size_t)b * NN + m0 + rr) * DD + o * 8;
        f32x4 u0 = *(const f32x4*)src;
        f32x4 u1 = *(const f32x4*)(src + 4);
        bf16x8 w;
        #pragma unroll
        for (int j = 0; j < 4; ++j) { w[j] = (__bf16)u0[j]; w[j + 4] = (__bf16)u1[j]; }
        *(bf16x8*)&As[rr * 64 + ((o ^ (rr & 7)) << 3)] = w;
    }
    #pragma unroll
    for (int it = 0; it < 2; ++it) {
        int lin = it * 256 + t;                  // 0..511
        int e  = lin >> 3;
        int d0 = lin & 7;
        const float* src = rproj + (size_t)e * DD + d0 * 8;
        f32x4 u0 = *(const f32x4*)src;
        f32x4 u1 = *(const f32x4*)(src + 4);
        #pragma unroll
        for (int j = 0; j < 8; ++j) {
            int d = d0 * 8 + j;
            float val = ((j < 4) ? u0[j] : u1[j - 4]) + (d == e ? 1.0f : 0.0f);
            Xs[d * 64 + (((e >> 3) ^ (d & 7)) << 3) + (e & 7)] = (__bf16)val;
        }
    }
    __syncthreads();

    f32x4 xp[4][2];
    #pragma unroll
    for (int mt = 0; mt < 4; ++mt)
        #pragma unroll
        for (int nt = 0; nt < 2; ++nt) xp[mt][nt] = zero;
    #pragma unroll
    for (int kk = 0; kk < DD; kk += 32) {
        int oc = (kk >> 3) + quad;
        bf16x8 af[4], bfr[2];
        #pragma unroll
        for (int mt = 0; mt < 4; ++mt) {
            int r = mrow0 + mt * 16 + ln;
            af[mt] = *(const bf16x8*)&As[r * 64 + ((oc ^ (r & 7)) << 3)];
        }
        #pragma unroll
        for (int nt = 0; nt < 2; ++nt) {
            int n = ncol0 + nt * 16 + ln;
            bfr[nt] = *(const bf16x8*)&Xs[n * 64 + ((oc ^ (n & 7)) << 3)];
        }
        #pragma unroll
        for (int mt = 0; mt < 4; ++mt)
            #pragma unroll
            for (int nt = 0; nt < 2; ++nt)
                xp[mt][nt] = __builtin_amdgcn_mfma_f32_16x16x32_bf16(
                    af[mt], bfr[nt], xp[mt][nt], 0, 0, 0);
    }

    // ---- epilogue: C/D layout col=lane&15, row=quad*4+reg ----
    #pragma unroll
    for (int mt = 0; mt < 4; ++mt) {
        #pragma unroll
        for (int rg = 0; rg < 4; ++rg) {
            float s = 0.f;
            #pragma unroll
            for (int nt = 0; nt < 2; ++nt) {
                float df = xp[mt][nt][rg] - acc[mt][nt][rg];
                s += df * df;
            }
            s += __shfl_xor(s, 1);
            s += __shfl_xor(s, 2);
            s += __shfl_xor(s, 4);
            s += __shfl_xor(s, 8);
            if (ln == 0) sred[mrow0 + mt * 16 + quad * 4 + rg][wave >> 1] = s;
        }
    }
    __syncthreads();
    if (t < 128) {
        float s = sred[t][0] + sred[t][1];
        int row = m0 + t;
        loss[(size_t)b * NN + row] =
            0.2f * sqrtf(s) + mxa[row] + 0.001f * sqrtf(ssa[row]);
    }
}

extern "C" void kernel_launch(void* const* d_in, const int* in_sizes, int n_in,
                              void* d_out, int out_size, void* d_ws, size_t ws_size,
                              hipStream_t stream) {
    const float* X   = (const float*)d_in[0];   // [B][N][D] f32
    const float* r   = (const float*)d_in[1];   // [D][D] f32
    const float* inc = (const float*)d_in[2];   // [N][N-1] f32
    float* out      = (float*)d_out;
    float* out_loss = out;                       // [B][N]
    float* out_inc  = out + (size_t)BB * NN;     // [N][N]

    char* ws = (char*)d_ws;
    float*  mxa = (float*)ws;
    float*  ssa = (float*)(ws + 16384);
    __bf16* XT  = (__bf16*)(ws + 32768);
    __bf16* A16 = (__bf16*)(ws + 32768 + (size_t)8 * 1024 * 1024);

    hipMemsetAsync(mxa, 0, 32768, stream);

    hipLaunchKernelGGL(build_kernel, dim3(NM1), dim3(256), 0, stream,
                       inc, out_inc, A16, mxa, ssa);
    hipLaunchKernelGGL(xt_kernel, dim3(NN / 64, BB), dim3(256), 0, stream,
                       X, XT, out_inc, A16);
    hipLaunchKernelGGL(gemm_loss_kernel, dim3(NN / 128, BB), dim3(256), 0, stream,
                       A16, XT, X, r, mxa, ssa, out_loss);
}